// Round 2
// baseline (270.448 us; speedup 1.0000x reference)
//
#include <hip/hip_runtime.h>
#include <cstdint>
#include <cstddef>

#define RHO 1e-8f
#define EPSV 1e-8f
#define THRESH 0.9f

typedef float v2f __attribute__((ext_vector_type(2)));

__device__ __forceinline__ float wave_max(float v) {
#pragma unroll
  for (int off = 1; off < 64; off <<= 1) v = fmaxf(v, __shfl_xor(v, off, 64));
  return v;
}

// ---------------- Stage 1: outer_forward -> (maxval, argmax) per (b, field) ----
// 4 fields per block, one wave per field, lane = mem row. x row broadcast via
// wave-uniform scalar loads (SGPR operands), packed-fp32 FMA, 4-acc ILP.
__global__ __launch_bounds__(256) void stage1_kernel(
    const float* __restrict__ xs, const float* __restrict__ mm0,
    float* __restrict__ maxv1, int* __restrict__ idx1) {
  const int lane = threadIdx.x & 63;
  const int f = __builtin_amdgcn_readfirstlane(blockIdx.x * 4 + (threadIdx.x >> 6));

  // my memory row (mem = lane), shifted by -0.5, in registers as float2 pairs
  const float* mrow = mm0 + ((size_t)f * 64 + lane) * 64;
  v2f m2[32];
#pragma unroll
  for (int j = 0; j < 16; ++j) {
    float4 v = reinterpret_cast<const float4*>(mrow)[j];
    m2[2 * j] = (v2f){v.x - 0.5f, v.y - 0.5f};
    m2[2 * j + 1] = (v2f){v.z - 0.5f, v.w - 0.5f};
  }
  v2f mn2 = (v2f){0.f, 0.f};
#pragma unroll
  for (int j = 0; j < 32; ++j) mn2 = m2[j] * m2[j] + mn2;
  const float mn = sqrtf(mn2.x + mn2.y);

  // x-row norms: lane b (mod 32) computes ||x[b,f,:]-0.5|| (dup lanes harmless)
  float xnv;
  {
    const int b = lane & 31;
    const float4* xr = reinterpret_cast<const float4*>(xs + ((size_t)b * 4096 + f) * 64);
    v2f s2 = (v2f){0.f, 0.f};
#pragma unroll
    for (int j = 0; j < 16; ++j) {
      float4 v = xr[j];
      v2f p0 = (v2f){v.x - 0.5f, v.y - 0.5f};
      v2f p1 = (v2f){v.z - 0.5f, v.w - 0.5f};
      s2 = p0 * p0 + s2;
      s2 = p1 * p1 + s2;
    }
    xnv = sqrtf(s2.x + s2.y);
  }

  const float* xfbase = xs + (size_t)f * 64;
#pragma clang loop unroll_count(1)
  for (int b = 0; b < 32; ++b) {
    // wave-uniform address -> scalar loads; SGPR srcs are free in v_pk_fma
    const float4* xq = reinterpret_cast<const float4*>(xfbase + (size_t)b * (4096 * 64));
    const float xnb = __shfl(xnv, b, 64);
    v2f a0 = {0.f, 0.f}, a1 = {0.f, 0.f}, a2 = {0.f, 0.f}, a3 = {0.f, 0.f};
#pragma unroll
    for (int j = 0; j < 16; j += 4) {
      float4 q0 = xq[j], q1 = xq[j + 1], q2 = xq[j + 2], q3 = xq[j + 3];
      a0 = m2[2 * j + 0] * ((v2f){q0.x, q0.y} - 0.5f) + a0;
      a0 = m2[2 * j + 1] * ((v2f){q0.z, q0.w} - 0.5f) + a0;
      a1 = m2[2 * j + 2] * ((v2f){q1.x, q1.y} - 0.5f) + a1;
      a1 = m2[2 * j + 3] * ((v2f){q1.z, q1.w} - 0.5f) + a1;
      a2 = m2[2 * j + 4] * ((v2f){q2.x, q2.y} - 0.5f) + a2;
      a2 = m2[2 * j + 5] * ((v2f){q2.z, q2.w} - 0.5f) + a2;
      a3 = m2[2 * j + 6] * ((v2f){q3.x, q3.y} - 0.5f) + a3;
      a3 = m2[2 * j + 7] * ((v2f){q3.z, q3.w} - 0.5f) + a3;
    }
    v2f as = (a0 + a1) + (a2 + a3);
    const float acc = as.x + as.y;
    const float val = (acc * 0.5f) / (mn * xnb + RHO) + 0.5f;
    const float mx = wave_max(val);
    unsigned long long t = __ballot(val == mx);
    int j0 = __ffsll((long long)t) - 1;  // first max index == jnp.argmax
    if (lane == 0) {
      maxv1[b * 4096 + f] = mx;
      idx1[b * 4096 + f] = j0;
    }
  }
}

// ---------------- Stage 2/3: hidden_forward (+ fused growth for GROW) ---------
// Block = node. Double-buffered single-child LDS tiles [h][k] stride 65
// (conflict-free both for staging writes and column gather). One barrier per
// child; next child prefetched into the alternate register set before the
// ds_write so loads stay in flight across the barrier.
template <int NFIN, int NODES, bool GROW>
__global__ __launch_bounds__(256) void hidden_kernel(
    const float* __restrict__ maxv_in, const int* __restrict__ idx_in,
    const float* __restrict__ mm,
    float* __restrict__ maxv_out, int* __restrict__ idx_out,
    const float* __restrict__ counts, float* __restrict__ out) {
  const int node = blockIdx.x;
  const int lane = threadIdx.x & 63;
  const int wave = threadIdx.x >> 6;
  const int tid = threadIdx.x;

  __shared__ float tile[2][64 * 65];  // 33,280 B
  __shared__ float hbuf[GROW ? 32 * 64 : 1];
  __shared__ float mxvS[GROW ? 32 : 1];
  __shared__ int idxS[GROW ? 32 : 1];
  __shared__ int trgS[GROW ? 32 : 1];
  __shared__ float cntS[GROW ? 64 : 1];
  __shared__ int sidxS[GROW ? 64 : 1];
  __shared__ int flagS[GROW ? 64 : 1];
  __shared__ int compS[GROW ? 64 : 1];
  __shared__ int selS[GROW ? 32 : 1];
  __shared__ float valS[GROW ? 32 : 1];
  __shared__ int keptS[1];

  const float* mmn = mm + (size_t)node * (8 * 4096);
  float4 A[4], B[4];
  {
    const float4* src = reinterpret_cast<const float4*>(mmn);
#pragma unroll
    for (int i = 0; i < 4; ++i) A[i] = src[tid + 256 * i];
  }
  float acc[8], s2[8];
#pragma unroll
  for (int i = 0; i < 8; ++i) { acc[i] = 0.f; s2[i] = 0.f; }

  const int bbase = wave * 8;
#pragma clang loop unroll_count(1)
  for (int c = 0; c < 8; ++c) {
    float4* cur = (c & 1) ? B : A;
    float4* nxt = (c & 1) ? A : B;
    if (c < 7) {  // prefetch next child; independent regs -> stays in flight
      const float4* src = reinterpret_cast<const float4*>(mmn + (size_t)(c + 1) * 4096);
#pragma unroll
      for (int i = 0; i < 4; ++i) nxt[i] = src[tid + 256 * i];
    }
    float* tb = tile[c & 1];
#pragma unroll
    for (int i = 0; i < 4; ++i) {
      int t4 = tid + 256 * i;  // over [h(6b)][kq(4b)]
      float* dst = &tb[(t4 >> 4) * 65 + (t4 & 15) * 4];
      dst[0] = cur[i].x; dst[1] = cur[i].y; dst[2] = cur[i].z; dst[3] = cur[i].w;
    }
    __syncthreads();
#pragma unroll
    for (int i = 0; i < 8; ++i) {
      const int b = bbase + i;
      const int off = __builtin_amdgcn_readfirstlane(b * NFIN + node * 8 + c);
      const int k = idx_in[off];
      const float v = maxv_in[off];
      acc[i] = fmaf(tb[lane * 65 + k], v, acc[i]);  // bank = (lane+k)%32, 2-way free
      s2[i] = fmaf(v, v, s2[i]);
    }
  }

#pragma unroll
  for (int i = 0; i < 8; ++i) {
    const int b = bbase + i;
    const float val = acc[i] / (8.f * sqrtf(s2[i]) + RHO);
    const float mx = wave_max(val);
    unsigned long long t = __ballot(val == mx);
    int j0 = __ffsll((long long)t) - 1;
    if constexpr (GROW) {
      hbuf[b * 64 + lane] = val;
      unsigned long long big = __ballot(val > THRESH);
      if (lane == 0) {
        mxvS[b] = mx; idxS[b] = j0; trgS[b] = (big == 0ULL) ? 1 : 0;
      }
    } else {
      if (lane == 0) {
        maxv_out[b * NODES + node] = mx;
        idx_out[b * NODES + node] = j0;
      }
    }
  }

  if constexpr (GROW) {
    // ---- growth_argmaxi, all data in LDS; barriers by full block ----
    if (tid < 64) { cntS[tid] = counts[node * 64 + tid]; flagS[tid] = 0; }
    __syncthreads();
    if (tid < 64) {  // stable ascending argsort of counts row
      float cl = cntS[tid];
      int rank = 0;
      for (int j = 0; j < 64; ++j) {
        float cj = cntS[j];
        rank += (cj < cl || (cj == cl && j < tid)) ? 1 : 0;
      }
      sidxS[rank] = tid;
    }
    __syncthreads();
    if (tid < 32) {  // reserved marks from non-triggered batches
      const int b = tid;
      if (!trgS[b]) {
        int j = idxS[b];
        float a = fabsf(mxvS[b]);
        int res;
        if (a > EPSV) res = j;             // unique positive max -> argsort[-1]=j
        else if (a == 0.f) res = 63;       // all-zero row: stable last = 63
        else if (a == EPSV) res = j;       // +inf at j
        else res = (j == 63) ? 62 : 63;    // negative entry: last zero wins
        flagS[res] = 1;
      }
    }
    __syncthreads();
    if (wave == 0) {  // stable compaction (move MARK to back)
      int s = sidxS[lane];
      int keep = flagS[s] ? 0 : 1;
      unsigned long long kb = __ballot(keep);
      int pos = __popcll(kb & ((1ULL << lane) - 1ULL));
      if (keep) compS[pos] = s;
      if (lane == 0) keptS[0] = __popcll(kb);
    }
    __syncthreads();
    if (tid < 32) {  // final index + value per batch
      const int b = tid;
      int fin = (b < keptS[0]) ? compS[b] : sidxS[b];
      int idxb; float a;
      if (trgS[b]) {
        idxb = fin;
        float v = hbuf[b * 64 + idxb];
        if (v == 0.f) v = 1.f;
        a = fabsf(v);
      } else {
        idxb = idxS[b];
        a = fabsf(mxvS[b]);
      }
      selS[b] = idxb;
      valS[b] = a / (a - EPSV);
    }
    __syncthreads();
#pragma unroll
    for (int r = 0; r < 8; ++r) {  // write (32,64) one-hot rows for this node
      int i = tid + 256 * r;
      int b = i >> 6, h = i & 63;
      out[((size_t)b * NODES + node) * 64 + h] = (h == selS[b]) ? valS[b] : 0.f;
    }
  }
}

extern "C" void kernel_launch(void* const* d_in, const int* in_sizes, int n_in,
                              void* d_out, int out_size, void* d_ws, size_t ws_size,
                              hipStream_t stream) {
  const float* xs = (const float*)d_in[0];      // (32, 4096, 64)
  const float* mm0 = (const float*)d_in[1];     // (4096, 64, 64)
  const float* mm1 = (const float*)d_in[2];     // (512, 8, 64, 64)
  const float* mm2 = (const float*)d_in[3];     // (64, 8, 64, 64)
  const float* counts = (const float*)d_in[4];  // (64, 64)
  float* out = (float*)d_out;                   // (32, 64, 64)
  char* ws = (char*)d_ws;

  float* maxv1 = (float*)(ws + 0);        // 32*4096 f32
  int* idx1 = (int*)(ws + 524288);        // 32*4096 i32
  float* maxv2 = (float*)(ws + 1048576);  // 32*512 f32
  int* idx2 = (int*)(ws + 1114112);       // 32*512 i32

  stage1_kernel<<<dim3(1024), dim3(256), 0, stream>>>(xs, mm0, maxv1, idx1);
  hidden_kernel<4096, 512, false><<<dim3(512), dim3(256), 0, stream>>>(
      maxv1, idx1, mm1, maxv2, idx2, nullptr, nullptr);
  hidden_kernel<512, 64, true><<<dim3(64), dim3(256), 0, stream>>>(
      maxv2, idx2, mm2, nullptr, nullptr, counts, out);
}